// Round 1
// baseline (260.394 us; speedup 1.0000x reference)
//
#include <hip/hip_runtime.h>

#define HH 1024
#define WW 1024
#define TH 32          // output rows per tile
#define TW 118         // output cols per tile
#define WL 128         // colsum width = TW + 10
#define SSIM_C1 1e-4f
#define SSIM_C2 9e-4f

__global__ void ssim_ws_init(float* ws) { ws[0] = 0.f; }

__global__ __launch_bounds__(256) void ssim_main(const float* __restrict__ img1,
                                                 const float* __restrict__ img2,
                                                 const float* __restrict__ window,
                                                 float* __restrict__ ws)
{
    __shared__ float4 cs4[TH][WL];   // 64 KB: interleaved colsums {s1,s2,(x+y)^2,(x-y)^2}

    const int tx = blockIdx.x;       // col tile: 0..8
    const int ty = blockIdx.y;       // row tile: 0..31
    const int b  = blockIdx.z;       // batch
    const int C0 = tx * TW;
    const int R0 = ty * TH;
    const int t  = threadIdx.x;
    const size_t ibase = (size_t)b * (size_t)(HH * WW);

    // ---- Phase 1: vertical running 11-row sums, one thread per colsum column ----
    if (t < WL) {
        const int col  = C0 + t - 5;
        const bool cok = (unsigned)col < (unsigned)WW;
        const float* px = img1 + ibase + col;
        const float* py = img2 + ibase + col;
        float rx[11], ry[11];        // 11-row register ring (static idx via full unroll)
        float s1 = 0.f, s2 = 0.f, sp = 0.f, sq = 0.f;
#pragma unroll
        for (int k = 0; k < TH + 10; ++k) {
            const int j = R0 - 5 + k;
            const bool ok = cok && ((unsigned)j < (unsigned)HH);
            float xv = 0.f, yv = 0.f;
            if (ok) {
                const size_t off = (size_t)j * WW;
                xv = px[off];
                yv = py[off];
            }
            const int slot = k % 11;           // compile-time under full unroll
            if (k >= 11) {                     // drop row leaving the 11-window
                const float ox = rx[slot], oy = ry[slot];
                const float oa = ox + oy, od = ox - oy;
                s1 -= ox; s2 -= oy; sp -= oa * oa; sq -= od * od;
            }
            rx[slot] = xv; ry[slot] = yv;
            const float a = xv + yv, d = xv - yv;
            s1 += xv; s2 += yv; sp += a * a; sq += d * d;
            if (k >= 10) {                     // emit colsum row r = k-10
                const int r = k - 10;
                float4 v; v.x = s1; v.y = s2; v.z = sp; v.w = sq;
                cs4[r][t ^ (r & 7)] = v;       // XOR swizzle (bank-conflict fix)
            }
        }
    }
    __syncthreads();

    // ---- Phase 2: horizontal 11-tap sliding window + SSIM ----
    const float w = window[0];                 // uniform 1/121 (taken from input)
    float ssum = 0.f;
    {
        const int r   = t & 31;
        const int seg = t >> 5;                // 8 segments of up to 15 output cols
        const int c0  = seg * 15;
        const int TWa = min(TW, WW - C0);      // ragged last col-tile (80 cols)
        const int S   = min(15, TWa - c0);
        if (S > 0) {
            const int rx7 = r & 7;
            float4 win; win.x = win.y = win.z = win.w = 0.f;
#pragma unroll
            for (int k = 0; k < 10; ++k) {
                const float4 v = cs4[r][(c0 + k) ^ rx7];
                win.x += v.x; win.y += v.y; win.z += v.z; win.w += v.w;
            }
            for (int p = 0; p < S; ++p) {
                const float4 v = cs4[r][(c0 + p + 10) ^ rx7];
                win.x += v.x; win.y += v.y; win.z += v.z; win.w += v.w;

                const float mu1  = win.x * w;
                const float mu2  = win.y * w;
                const float P    = win.z * w;  // box((x+y)^2)
                const float Q    = win.w * w;  // box((x-y)^2)
                const float mu11 = mu1 * mu1;
                const float mu22 = mu2 * mu2;
                const float mu12 = mu1 * mu2;
                const float sigs = 0.5f  * (P + Q) - mu11 - mu22; // sig1^2+sig2^2
                const float s12  = 0.25f * (P - Q) - mu12;        // sig12
                const float num  = (2.f * mu12 + SSIM_C1) * (2.f * s12 + SSIM_C2);
                const float den  = (mu11 + mu22 + SSIM_C1) * (sigs + SSIM_C2);
                ssum += num / den;

                const float4 o = cs4[r][(c0 + p) ^ rx7];
                win.x -= o.x; win.y -= o.y; win.z -= o.z; win.w -= o.w;
            }
        }
    }

    // ---- Block reduction -> one atomicAdd ----
    float v = ssum;
#pragma unroll
    for (int off = 32; off > 0; off >>= 1) v += __shfl_down(v, off, 64);
    __syncthreads();                            // all LDS reads done; reuse cs4
    float* red = (float*)&cs4[0][0];
    if ((t & 63) == 0) red[t >> 6] = v;
    __syncthreads();
    if (t == 0) atomicAdd(ws, red[0] + red[1] + red[2] + red[3]);
}

__global__ void ssim_fin(const float* __restrict__ ws, float* __restrict__ out, int ntot) {
    out[0] = 1.f - ws[0] / (float)ntot;
}

extern "C" void kernel_launch(void* const* d_in, const int* in_sizes, int n_in,
                              void* d_out, int out_size, void* d_ws, size_t ws_size,
                              hipStream_t stream) {
    const float* img1 = (const float*)d_in[0];
    const float* img2 = (const float*)d_in[1];
    const float* win  = (const float*)d_in[2];
    float* out = (float*)d_out;
    float* ws  = (float*)d_ws;
    const int ntot = in_sizes[0];                       // 32*1024*1024
    const int batches = ntot / (HH * WW);               // 32

    ssim_ws_init<<<dim3(1), dim3(1), 0, stream>>>(ws);
    dim3 grid((WW + TW - 1) / TW, HH / TH, batches);    // 9 x 32 x 32
    ssim_main<<<grid, dim3(256), 0, stream>>>(img1, img2, win, ws);
    ssim_fin<<<dim3(1), dim3(1), 0, stream>>>(ws, out, ntot);
}